// Round 1
// baseline (383.741 us; speedup 1.0000x reference)
//
#include <hip/hip_runtime.h>

#define HH 128
#define WW 128
#define BB 4
#define CC 64
#define CHN 21
#define NPIX (HH*WW)
#define NTAP 24

__device__ __forceinline__ int clampi(int v, int lo, int hi) {
    return v < lo ? lo : (v > hi ? hi : v);
}

// Build the 24 clamped neighbor offsets (dilations 1,2,4; 3x3 minus center),
// in the same enumeration order as the reference's neighbors() concat.
__device__ __forceinline__ void build_offsets(int h, int w, int* off) {
    const int dil[3] = {1, 2, 4};
    int n = 0;
    #pragma unroll
    for (int dd = 0; dd < 3; ++dd) {
        int d = dil[dd];
        #pragma unroll
        for (int i = 0; i < 3; ++i) {
            #pragma unroll
            for (int j = 0; j < 3; ++j) {
                if (i == 1 && j == 1) continue;
                int r = clampi(h + (i - 1) * d, 0, HH - 1);
                int c = clampi(w + (j - 1) * d, 0, WW - 1);
                off[n++] = r * WW + c;
            }
        }
    }
}

__global__ __launch_bounds__(256) void affinity_kernel(
    const float* __restrict__ feats, float* __restrict__ aff) {
    int idx = blockIdx.x * blockDim.x + threadIdx.x;   // 0 .. B*NPIX-1
    int w = idx & (WW - 1);
    int h = (idx >> 7) & (HH - 1);
    int b = idx >> 14;

    int off[NTAP];
    build_offsets(h, w, off);

    float acc[NTAP];
    #pragma unroll
    for (int k = 0; k < NTAP; ++k) acc[k] = 0.f;

    const float* fb = feats + (size_t)b * CC * NPIX;
    const int center = h * WW + w;

    for (int c = 0; c < CC; ++c) {
        const float* fp = fb + (size_t)c * NPIX;
        float q = fp[center];
        float v[NTAP];
        // std over 27 windows: the center window appears once per dilation (3x)
        float sum = 3.f * q, sumsq = 3.f * q * q;
        #pragma unroll
        for (int k = 0; k < NTAP; ++k) {
            float x = fp[off[k]];
            v[k] = x;
            sum += x;
            sumsq += x * x;
        }
        float var = (sumsq - sum * sum * (1.0f / 27.0f)) * (1.0f / 26.0f);
        float sd = sqrtf(fmaxf(var, 0.f));
        float inv = 1.0f / (1e-8f + 0.1f * sd);
        #pragma unroll
        for (int k = 0; k < NTAP; ++k) acc[k] -= fabsf(v[k] - q) * inv;
    }

    // mean over channels, softmax over the 24 taps
    float m = -1e30f;
    #pragma unroll
    for (int k = 0; k < NTAP; ++k) {
        acc[k] *= (1.0f / CC);
        m = fmaxf(m, acc[k]);
    }
    float s = 0.f;
    #pragma unroll
    for (int k = 0; k < NTAP; ++k) {
        acc[k] = expf(acc[k] - m);
        s += acc[k];
    }
    float invs = 1.0f / s;

    float* ab = aff + (size_t)b * NTAP * NPIX + center;
    #pragma unroll
    for (int k = 0; k < NTAP; ++k) ab[(size_t)k * NPIX] = acc[k] * invs;
}

__global__ __launch_bounds__(256) void prop_kernel(
    const float* __restrict__ src, const float* __restrict__ aff,
    float* __restrict__ dst) {
    int idx = blockIdx.x * blockDim.x + threadIdx.x;
    int w = idx & (WW - 1);
    int h = (idx >> 7) & (HH - 1);
    int b = idx >> 14;

    int off[NTAP];
    build_offsets(h, w, off);

    const int center = h * WW + w;
    float a[NTAP];
    const float* ab = aff + (size_t)b * NTAP * NPIX + center;
    #pragma unroll
    for (int k = 0; k < NTAP; ++k) a[k] = ab[(size_t)k * NPIX];

    const float* sb = src + (size_t)b * CHN * NPIX;
    float* db = dst + (size_t)b * CHN * NPIX;
    for (int ch = 0; ch < CHN; ++ch) {
        const float* mp = sb + (size_t)ch * NPIX;
        float r = 0.f;
        #pragma unroll
        for (int k = 0; k < NTAP; ++k) r += a[k] * mp[off[k]];
        db[(size_t)ch * NPIX + center] = r;
    }
}

extern "C" void kernel_launch(void* const* d_in, const int* in_sizes, int n_in,
                              void* d_out, int out_size, void* d_ws, size_t ws_size,
                              hipStream_t stream) {
    const float* feats = (const float*)d_in[0];
    const float* mask  = (const float*)d_in[1];
    float* out = (float*)d_out;

    float* aff = (float*)d_ws;                          // B*24*NPIX floats = 6.3 MB
    float* buf = aff + (size_t)BB * NTAP * NPIX;        // B*21*NPIX floats = 5.5 MB

    const int totalPix = BB * NPIX;                     // 65536
    dim3 blk(256), grd(totalPix / 256);

    affinity_kernel<<<grd, blk, 0, stream>>>(feats, aff);

    // 10 propagation iterations; even iterations write d_out so iter 10 ends there
    const float* src = mask;
    for (int it = 1; it <= 10; ++it) {
        float* dst = (it & 1) ? buf : out;
        prop_kernel<<<grd, blk, 0, stream>>>(src, aff, dst);
        src = dst;
    }
}

// Round 2
// 133.032 us; speedup vs baseline: 2.8846x; 2.8846x over previous
//
#include <hip/hip_runtime.h>

#define HH 128
#define WW 128
#define BB 4
#define CC 64
#define CHN 21
#define NPIX (HH*WW)
#define NTAP 24
#define CG 3            // channels per prop thread
#define NCG (CHN/CG)    // 7 channel groups

__device__ __forceinline__ int clampi(int v, int lo, int hi) {
    return v < lo ? lo : (v > hi ? hi : v);
}

// Build the 24 clamped neighbor offsets (dilations 1,2,4; 3x3 minus center),
// in the same enumeration order as the reference's neighbors() concat.
__device__ __forceinline__ void build_offsets(int h, int w, int* off) {
    const int dil[3] = {1, 2, 4};
    int n = 0;
    #pragma unroll
    for (int dd = 0; dd < 3; ++dd) {
        int d = dil[dd];
        #pragma unroll
        for (int i = 0; i < 3; ++i) {
            #pragma unroll
            for (int j = 0; j < 3; ++j) {
                if (i == 1 && j == 1) continue;
                int r = clampi(h + (i - 1) * d, 0, HH - 1);
                int c = clampi(w + (j - 1) * d, 0, WW - 1);
                off[n++] = r * WW + c;
            }
        }
    }
}

// ---- affinity: partial accumulation over a channel group --------------------
__global__ __launch_bounds__(256) void partial_affinity_kernel(
    const float* __restrict__ feats, float* __restrict__ partial, int cpg) {
    int idx = blockIdx.x * blockDim.x + threadIdx.x;   // 0 .. B*NPIX-1
    int g = blockIdx.y;
    int w = idx & (WW - 1);
    int h = (idx >> 7) & (HH - 1);
    int b = idx >> 14;

    int off[NTAP];
    build_offsets(h, w, off);

    float acc[NTAP];
    #pragma unroll
    for (int k = 0; k < NTAP; ++k) acc[k] = 0.f;

    const float* fb = feats + (size_t)b * CC * NPIX;
    const int center = h * WW + w;

    int c0 = g * cpg;
    for (int c = c0; c < c0 + cpg; ++c) {
        const float* fp = fb + (size_t)c * NPIX;
        float q = fp[center];
        float v[NTAP];
        float sum = 3.f * q, sumsq = 3.f * q * q;   // center window x3 dilations
        #pragma unroll
        for (int k = 0; k < NTAP; ++k) {
            float x = fp[off[k]];
            v[k] = x;
            sum += x;
            sumsq += x * x;
        }
        float var = (sumsq - sum * sum * (1.0f / 27.0f)) * (1.0f / 26.0f);
        float sd = sqrtf(fmaxf(var, 0.f));
        float inv = 1.0f / (1e-8f + 0.1f * sd);
        #pragma unroll
        for (int k = 0; k < NTAP; ++k) acc[k] -= fabsf(v[k] - q) * inv;
    }

    float* pb = partial + ((size_t)g * BB + b) * NTAP * NPIX + center;
    #pragma unroll
    for (int k = 0; k < NTAP; ++k) pb[(size_t)k * NPIX] = acc[k];
}

__global__ __launch_bounds__(256) void finalize_affinity_kernel(
    const float* __restrict__ partial, float* __restrict__ aff, int G) {
    int idx = blockIdx.x * blockDim.x + threadIdx.x;
    int b = idx >> 14;
    int pix = idx & (NPIX - 1);

    float acc[NTAP];
    #pragma unroll
    for (int k = 0; k < NTAP; ++k) acc[k] = 0.f;
    for (int g = 0; g < G; ++g) {
        const float* pb = partial + ((size_t)g * BB + b) * NTAP * NPIX + pix;
        #pragma unroll
        for (int k = 0; k < NTAP; ++k) acc[k] += pb[(size_t)k * NPIX];
    }

    float m = -1e30f;
    #pragma unroll
    for (int k = 0; k < NTAP; ++k) {
        acc[k] *= (1.0f / CC);
        m = fmaxf(m, acc[k]);
    }
    float s = 0.f;
    #pragma unroll
    for (int k = 0; k < NTAP; ++k) {
        acc[k] = expf(acc[k] - m);
        s += acc[k];
    }
    float invs = 1.0f / s;
    float* ab = aff + (size_t)b * NTAP * NPIX + pix;
    #pragma unroll
    for (int k = 0; k < NTAP; ++k) ab[(size_t)k * NPIX] = acc[k] * invs;
}

// ---- monolithic affinity fallback (small ws) --------------------------------
__global__ __launch_bounds__(256) void affinity_kernel(
    const float* __restrict__ feats, float* __restrict__ aff) {
    int idx = blockIdx.x * blockDim.x + threadIdx.x;
    int w = idx & (WW - 1);
    int h = (idx >> 7) & (HH - 1);
    int b = idx >> 14;

    int off[NTAP];
    build_offsets(h, w, off);

    float acc[NTAP];
    #pragma unroll
    for (int k = 0; k < NTAP; ++k) acc[k] = 0.f;

    const float* fb = feats + (size_t)b * CC * NPIX;
    const int center = h * WW + w;

    for (int c = 0; c < CC; ++c) {
        const float* fp = fb + (size_t)c * NPIX;
        float q = fp[center];
        float v[NTAP];
        float sum = 3.f * q, sumsq = 3.f * q * q;
        #pragma unroll
        for (int k = 0; k < NTAP; ++k) {
            float x = fp[off[k]];
            v[k] = x;
            sum += x;
            sumsq += x * x;
        }
        float var = (sumsq - sum * sum * (1.0f / 27.0f)) * (1.0f / 26.0f);
        float sd = sqrtf(fmaxf(var, 0.f));
        float inv = 1.0f / (1e-8f + 0.1f * sd);
        #pragma unroll
        for (int k = 0; k < NTAP; ++k) acc[k] -= fabsf(v[k] - q) * inv;
    }

    float m = -1e30f;
    #pragma unroll
    for (int k = 0; k < NTAP; ++k) {
        acc[k] *= (1.0f / CC);
        m = fmaxf(m, acc[k]);
    }
    float s = 0.f;
    #pragma unroll
    for (int k = 0; k < NTAP; ++k) {
        acc[k] = expf(acc[k] - m);
        s += acc[k];
    }
    float invs = 1.0f / s;
    float* ab = aff + (size_t)b * NTAP * NPIX + center;
    #pragma unroll
    for (int k = 0; k < NTAP; ++k) ab[(size_t)k * NPIX] = acc[k] * invs;
}

// ---- propagation: gridDim.y = 7 channel groups of 3 -------------------------
__global__ __launch_bounds__(256) void prop_kernel(
    const float* __restrict__ src, const float* __restrict__ aff,
    float* __restrict__ dst) {
    int idx = blockIdx.x * blockDim.x + threadIdx.x;
    int cg = blockIdx.y;
    int w = idx & (WW - 1);
    int h = (idx >> 7) & (HH - 1);
    int b = idx >> 14;

    int off[NTAP];
    build_offsets(h, w, off);

    const int center = h * WW + w;
    float a[NTAP];
    const float* ab = aff + (size_t)b * NTAP * NPIX + center;
    #pragma unroll
    for (int k = 0; k < NTAP; ++k) a[k] = ab[(size_t)k * NPIX];

    const float* sb = src + (size_t)b * CHN * NPIX;
    float* db = dst + (size_t)b * CHN * NPIX;
    #pragma unroll
    for (int cc = 0; cc < CG; ++cc) {
        int ch = cg * CG + cc;
        const float* mp = sb + (size_t)ch * NPIX;
        float r = 0.f;
        #pragma unroll
        for (int k = 0; k < NTAP; ++k) r += a[k] * mp[off[k]];
        db[(size_t)ch * NPIX + center] = r;
    }
}

extern "C" void kernel_launch(void* const* d_in, const int* in_sizes, int n_in,
                              void* d_out, int out_size, void* d_ws, size_t ws_size,
                              hipStream_t stream) {
    const float* feats = (const float*)d_in[0];
    const float* mask  = (const float*)d_in[1];
    float* out = (float*)d_out;

    const size_t affElems = (size_t)BB * NTAP * NPIX;   // 1.57 M floats
    const size_t bufElems = (size_t)BB * CHN * NPIX;    // 1.38 M floats

    float* aff = (float*)d_ws;
    float* buf = aff + affElems;
    float* partial = buf + bufElems;

    const int totalPix = BB * NPIX;                     // 65536
    dim3 blk(256);
    dim3 grd(totalPix / 256);

    // Pick channel-split factor G for affinity based on available workspace.
    size_t baseBytes = (affElems + bufElems) * sizeof(float);
    int G = 0;
    for (int g = 8; g >= 2; g >>= 1) {
        if (baseBytes + (size_t)g * affElems * sizeof(float) <= ws_size) { G = g; break; }
    }

    if (G >= 2) {
        dim3 grdG(totalPix / 256, G);
        partial_affinity_kernel<<<grdG, blk, 0, stream>>>(feats, partial, CC / G);
        finalize_affinity_kernel<<<grd, blk, 0, stream>>>(partial, aff, G);
    } else {
        affinity_kernel<<<grd, blk, 0, stream>>>(feats, aff);
    }

    // 10 propagation iterations; even iterations write d_out so iter 10 ends there
    dim3 grdP(totalPix / 256, NCG);
    const float* src = mask;
    for (int it = 1; it <= 10; ++it) {
        float* dst = (it & 1) ? buf : out;
        prop_kernel<<<grdP, blk, 0, stream>>>(src, aff, dst);
        src = dst;
    }
}